// Round 20
// baseline (1679.897 us; speedup 1.0000x reference)
//
#include <hip/hip_runtime.h>
#include <cmath>

#define S_LEN 32
#define E_DIM 128
#define H_DIM 256
#define V_DIM 512
#define NTILE 12            // h-only K=256: 0-3 a1w1, 4-7 a1w2s, 8-11 a2s*w1
#define W_TILES 8
#define TILE_SHORTS 8192
#define A_SHORTS 8192       // per level: 16 KB
#define ZPITCH 132

typedef _Float16 f16x8v __attribute__((ext_vector_type(8)));
typedef float f32x16 __attribute__((ext_vector_type(16)));

#define SCALE_S 4096.0f
#define INV_S   2.44140625e-4f

__device__ __forceinline__ float sigf(float x) { return 1.0f / (1.0f + expf(-x)); }

template<int L>
__device__ __forceinline__ unsigned short lvl_f16(float x) {
  _Float16 h1 = (_Float16)x;
  if (L == 1) return __builtin_bit_cast(unsigned short, h1);
  _Float16 h2 = (_Float16)((x - (float)h1) * SCALE_S);
  return __builtin_bit_cast(unsigned short, h2);
}

// ---- agent-scope float4 transport (bit-exact, L1-bypassing) ---------------
__device__ __forceinline__ float4 aload4(const float* p) {
  const unsigned long long* q = (const unsigned long long*)p;
  unsigned long long u0 = __hip_atomic_load(q,     __ATOMIC_RELAXED, __HIP_MEMORY_SCOPE_AGENT);
  unsigned long long u1 = __hip_atomic_load(q + 1, __ATOMIC_RELAXED, __HIP_MEMORY_SCOPE_AGENT);
  float4 v;
  v.x = __uint_as_float((unsigned)u0); v.y = __uint_as_float((unsigned)(u0 >> 32));
  v.z = __uint_as_float((unsigned)u1); v.w = __uint_as_float((unsigned)(u1 >> 32));
  return v;
}
__device__ __forceinline__ void astore4(float* p, float4 v) {
  unsigned long long u0 = (unsigned long long)__float_as_uint(v.x)
                        | ((unsigned long long)__float_as_uint(v.y) << 32);
  unsigned long long u1 = (unsigned long long)__float_as_uint(v.z)
                        | ((unsigned long long)__float_as_uint(v.w) << 32);
  __hip_atomic_store((unsigned long long*)p,     u0, __ATOMIC_RELAXED, __HIP_MEMORY_SCOPE_AGENT);
  __hip_atomic_store((unsigned long long*)p + 1, u1, __ATOMIC_RELAXED, __HIP_MEMORY_SCOPE_AGENT);
}

// ---- group flag sync (8 blocks), r10-proven protocol ----------------------
__device__ __forceinline__ void group_wait(int* flag, int target) {
  if (threadIdx.x == 0) {
    while (__hip_atomic_load(flag, __ATOMIC_ACQUIRE, __HIP_MEMORY_SCOPE_AGENT) < target)
      __builtin_amdgcn_s_sleep(2);
  }
  __syncthreads();
}
__device__ __forceinline__ void group_arrive(int* flag) {
  __syncthreads();
  if (threadIdx.x == 0)
    __hip_atomic_fetch_add(flag, 1, __ATOMIC_RELEASE, __HIP_MEMORY_SCOPE_AGENT);
}

// ---------------------------------------------------------------------------
// prep — r19 roles + init tail zeroes hB, c, tok, flags.
// ---------------------------------------------------------------------------
__global__ void prep_weights(const float* __restrict__ eemb, const float* __restrict__ demb,
                             const float* __restrict__ eWih, const float* __restrict__ eWhh,
                             const float* __restrict__ dWih, const float* __restrict__ dWhh,
                             unsigned short* __restrict__ We, unsigned short* __restrict__ Wd,
                             float* __restrict__ PE, float* __restrict__ PD,
                             float* __restrict__ hB, float* __restrict__ c,
                             int* __restrict__ tok, int* __restrict__ flags)
{
  const int b = blockIdx.x;
  if (b >= 1152) {                        // init tail: 64 blocks
    const int pb = b - 1152;
    const int gt = pb * 256 + threadIdx.x;
    float4 z = make_float4(0.f, 0.f, 0.f, 0.f);
    float4* p0 = (float4*)hB;
    float4* pc = (float4*)c;
    for (int i = gt; i < 131072; i += 16384) { p0[i] = z; pc[i] = z; }
    if (gt < 2048) tok[gt] = 0;
    if (gt < 64) flags[gt] = 0;
    return;
  }
  if (b >= 128) {                         // precomp P = emb @ Wih^T (exact f32)
    const int pb  = b - 128;
    const int set = pb >> 9;
    const int v   = pb & 511;
    const float* Wih  = set ? dWih : eWih;
    const float* embr = (set ? demb : eemb) + (size_t)v * E_DIM;
    float* dst = (set ? PD : PE) + (size_t)v * 1024;
    const int n0 = threadIdx.x * 4;
    float acc[4] = {0.f, 0.f, 0.f, 0.f};
    #pragma unroll 4
    for (int k0 = 0; k0 < E_DIM; k0 += 4) {
      float4 e = *(const float4*)(embr + k0);
      #pragma unroll
      for (int i = 0; i < 4; ++i) {
        float4 wv = *(const float4*)(Wih + (size_t)(n0 + i) * E_DIM + k0);
        acc[i] = fmaf(e.x, wv.x, acc[i]);
        acc[i] = fmaf(e.y, wv.y, acc[i]);
        acc[i] = fmaf(e.z, wv.z, acc[i]);
        acc[i] = fmaf(e.w, wv.w, acc[i]);
      }
    }
    *(float4*)(dst + n0) = make_float4(acc[0], acc[1], acc[2], acc[3]);
    return;
  }
  // Whh fragment stream (32x32x16 layout, fp16 2-level)
  const int j    = b % W_TILES;
  const int rest = b / W_TILES;
  const int nb   = rest & 7;
  const int set  = rest >> 3;
  const float* Whh = set ? dWhh : eWhh;
  unsigned short* dst = (set ? Wd : We) + ((size_t)nb * W_TILES + j) * TILE_SHORTS;
  const int lvl = (j < 4) ? 1 : 2;
  const int jj  = j & 3;

  for (int cpos = threadIdx.x; cpos < 1024; cpos += 256) {
    int fi = cpos >> 6, l = cpos & 63;
    int g = fi >> 2, kc = fi & 3;
    int n  = g * H_DIM + nb * 32 + (l & 31);
    int kk = jj * 64 + kc * 16 + (l >> 5) * 8;
    unsigned short o8[8];
    #pragma unroll
    for (int e = 0; e < 8; ++e) {
      float v = Whh[(size_t)n * H_DIM + kk + e];
      o8[e] = (lvl == 1) ? lvl_f16<1>(v) : lvl_f16<2>(v);
    }
    uint4 pk;
    pk.x = (unsigned)o8[0] | ((unsigned)o8[1] << 16);
    pk.y = (unsigned)o8[2] | ((unsigned)o8[3] << 16);
    pk.z = (unsigned)o8[4] | ((unsigned)o8[5] << 16);
    pk.w = (unsigned)o8[6] | ((unsigned)o8[7] << 16);
    *(uint4*)&dst[(size_t)cpos * 8] = pk;
  }
}

// stage both fp16 levels of h (K=256) into 32x32x16 A layout; src via atomics
__device__ __forceinline__ void stage_A12m(unsigned short* Ax1, unsigned short* Ax2,
                                           const float* hsrc, int arow, int q8) {
  #pragma unroll
  for (int j = 0; j < 8; ++j) {
    int kA = q8 * 4 + 32 * j;
    float4 v = aload4(hsrc + kA);
    _Float16 a1x = (_Float16)v.x, a1y = (_Float16)v.y,
             a1z = (_Float16)v.z, a1w = (_Float16)v.w;
    _Float16 a2x = (_Float16)((v.x - (float)a1x) * SCALE_S);
    _Float16 a2y = (_Float16)((v.y - (float)a1y) * SCALE_S);
    _Float16 a2z = (_Float16)((v.z - (float)a1z) * SCALE_S);
    _Float16 a2w = (_Float16)((v.w - (float)a1w) * SCALE_S);
    int lane_w = arow + ((kA >> 3) & 1) * 32;
    int idx = ((kA >> 4) * 64 + lane_w) * 8 + (kA & 7);
    uint2 p1, p2;
    p1.x = (unsigned)__builtin_bit_cast(unsigned short, a1x)
         | ((unsigned)__builtin_bit_cast(unsigned short, a1y) << 16);
    p1.y = (unsigned)__builtin_bit_cast(unsigned short, a1z)
         | ((unsigned)__builtin_bit_cast(unsigned short, a1w) << 16);
    p2.x = (unsigned)__builtin_bit_cast(unsigned short, a2x)
         | ((unsigned)__builtin_bit_cast(unsigned short, a2y) << 16);
    p2.y = (unsigned)__builtin_bit_cast(unsigned short, a2z)
         | ((unsigned)__builtin_bit_cast(unsigned short, a2w) << 16);
    *(uint2*)&Ax1[idx] = p1;
    *(uint2*)&Ax2[idx] = p2;
  }
}

// (f32-source variant for the fallback kernel)
__device__ __forceinline__ void stage_A12(unsigned short* Ax1, unsigned short* Ax2,
                                          const float* __restrict__ hsrc,
                                          int arow, int q8) {
  #pragma unroll
  for (int j = 0; j < 8; ++j) {
    int kA = q8 * 4 + 32 * j;
    float4 v = *(const float4*)(hsrc + kA);
    _Float16 a1x = (_Float16)v.x, a1y = (_Float16)v.y,
             a1z = (_Float16)v.z, a1w = (_Float16)v.w;
    _Float16 a2x = (_Float16)((v.x - (float)a1x) * SCALE_S);
    _Float16 a2y = (_Float16)((v.y - (float)a1y) * SCALE_S);
    _Float16 a2z = (_Float16)((v.z - (float)a1z) * SCALE_S);
    _Float16 a2w = (_Float16)((v.w - (float)a1w) * SCALE_S);
    int lane_w = arow + ((kA >> 3) & 1) * 32;
    int idx = ((kA >> 4) * 64 + lane_w) * 8 + (kA & 7);
    uint2 p1, p2;
    p1.x = (unsigned)__builtin_bit_cast(unsigned short, a1x)
         | ((unsigned)__builtin_bit_cast(unsigned short, a1y) << 16);
    p1.y = (unsigned)__builtin_bit_cast(unsigned short, a1z)
         | ((unsigned)__builtin_bit_cast(unsigned short, a1w) << 16);
    p2.x = (unsigned)__builtin_bit_cast(unsigned short, a2x)
         | ((unsigned)__builtin_bit_cast(unsigned short, a2y) << 16);
    p2.y = (unsigned)__builtin_bit_cast(unsigned short, a2z)
         | ((unsigned)__builtin_bit_cast(unsigned short, a2w) << 16);
    *(uint2*)&Ax1[idx] = p1;
    *(uint2*)&Ax2[idx] = p2;
  }
}

#define LOADT(J, P)                                                            \
  {                                                                            \
    const unsigned short* bsrc = wb + (size_t)((J) & 7) * TILE_SHORTS;         \
    _Pragma("unroll")                                                          \
    for (int kc = 0; kc < 4; ++kc) P[kc] = *(const uint4*)(bsrc + (size_t)kc * 512); \
  }

#define MFMAT(J, P, ACCX, AXB)                                                 \
  {                                                                            \
    _Pragma("unroll")                                                          \
    for (int kc = 0; kc < 4; ++kc) {                                           \
      f16x8v af = *(const f16x8v*)&AXB[(((J) & 3) * 4 + kc) * 512 + lane * 8]; \
      f16x8v bfr = __builtin_bit_cast(f16x8v, P[kc]);                          \
      ACCX = __builtin_amdgcn_mfma_f32_32x32x16_f16(af, bfr, ACCX, 0, 0, 0);   \
    }                                                                          \
  }

// ---------------------------------------------------------------------------
// MEGA: all 80 steps + decoder logits/argmax, one launch. 512 blocks x 256.
// Block (g = bid&63, nb = bid>>6): lstm rows g*32..+31 x cols nb*32..+31;
// decoder declog rows g*32+nb*4..+3 (all comms within the 8-block group,
// bids ≡ g mod 8 -> same XCD). c lives in registers for all 80 steps.
// ---------------------------------------------------------------------------
__launch_bounds__(256, 2)
__global__ void seq2seq_mega(
    const int* __restrict__ source,
    const float* __restrict__ PE, const float* __restrict__ PD,
    const unsigned short* __restrict__ We, const unsigned short* __restrict__ Wd,
    const float* __restrict__ ebih, const float* __restrict__ ebhh,
    const float* __restrict__ dbih, const float* __restrict__ dbhh,
    const float* __restrict__ fcW, const float* __restrict__ fcb,
    float* __restrict__ out, float* __restrict__ hA, float* __restrict__ hB,
    int* __restrict__ tok, int* __restrict__ flags, int T)
{
  __shared__ __align__(16) unsigned short smem[2 * A_SHORTS];  // 32 KB
  unsigned short* Ax1 = smem;
  unsigned short* Ax2 = smem + A_SHORTS;

  const int tid  = threadIdx.x;
  const int lane = tid & 63;
  const int w    = tid >> 6;
  const int bid  = blockIdx.x;
  const int g    = bid & 63;
  const int nb   = bid >> 6;
  const int m0   = g * 32;
  const int nc0  = nb * 32;
  int* flag = &flags[g];
  int E = 0;

  const int arow = tid >> 3;       // 0..31 (== epilogue row er)
  const int q8   = tid & 7;        // (== epilogue col group ec)
  const int col32 = lane & 31;
  const int lhi   = lane >> 5;

  const float ebs = ebih[w * H_DIM + nc0 + col32] + ebhh[w * H_DIM + nc0 + col32];
  const float dbs = dbih[w * H_DIM + nc0 + col32] + dbhh[w * H_DIM + nc0 + col32];

  float c_reg[4] = {0.f, 0.f, 0.f, 0.f};

  const int nsteps = S_LEN + T;
  for (int s = 0; s < nsteps; ++s) {
    const bool enc = (s < S_LEN);

    // ================= LSTM epoch =================
    group_wait(flag, 8 * E);

    int token;
    if (enc)            token = source[(size_t)(m0 + arow) * S_LEN + s];
    else if (s == S_LEN) token = 0;
    else                 token = __hip_atomic_load(&tok[m0 + arow], __ATOMIC_RELAXED,
                                                   __HIP_MEMORY_SCOPE_AGENT);

    const float* hprev = (s & 1) ? hA : hB;       // R(s); hB zero-init for s=0
    const float* hsrc  = hprev + (size_t)(m0 + arow) * H_DIM;
    const unsigned short* wb = (enc ? We : Wd) + (size_t)nb * (W_TILES * TILE_SHORTS)
                             + (size_t)(w * 4) * 512 + (size_t)lane * 8;

    f32x16 accA, accB;
    #pragma unroll
    for (int r = 0; r < 16; ++r) { accA[r] = 0.f; accB[r] = 0.f; }

    uint4 pA[4], pB[4], pC[4], pD[4];

    LOADT(0, pA); LOADT(1, pB); LOADT(2, pC);

    stage_A12m(Ax1, Ax2, hsrc, arow, q8);
    asm volatile("s_waitcnt lgkmcnt(0)" ::: "memory");
    __builtin_amdgcn_s_barrier();

    LOADT(3, pD);  MFMAT(0, pA, accA, Ax1);
    LOADT(4, pA);  MFMAT(1, pB, accA, Ax1);
    LOADT(5, pB);  MFMAT(2, pC, accA, Ax1);
    LOADT(6, pC);  MFMAT(3, pD, accA, Ax1);
    LOADT(7, pD);  MFMAT(4, pA, accB, Ax1);
    LOADT(8, pA);  MFMAT(5, pB, accB, Ax1);
    LOADT(9, pB);  MFMAT(6, pC, accB, Ax1);
    LOADT(10, pC); MFMAT(7, pD, accB, Ax1);
    LOADT(11, pD); MFMAT(8, pA, accB, Ax2);

    // prefetch precomp-x rows (normal loads; PE/PD read-only)
    const float* pxr = (enc ? PE : PD) + (size_t)token * 1024 + nc0 + q8 * 4;
    float pxa[4][4];
    #pragma unroll
    for (int gg = 0; gg < 4; ++gg) {
      float4 t = *(const float4*)(pxr + gg * H_DIM);
      pxa[gg][0] = t.x; pxa[gg][1] = t.y; pxa[gg][2] = t.z; pxa[gg][3] = t.w;
    }

    MFMAT(9, pB, accB, Ax2);
    MFMAT(10, pC, accB, Ax2);
    MFMAT(11, pD, accB, Ax2);

    // epilogue stage 1: z -> LDS (alias A)
    const float bsv = enc ? ebs : dbs;
    float* zb = (float*)smem;
    asm volatile("s_waitcnt lgkmcnt(0)" ::: "memory");
    __builtin_amdgcn_s_barrier();

    #pragma unroll
    for (int r = 0; r < 16; ++r) {
      int row_l = (r & 3) + 8 * (r >> 2) + 4 * lhi;
      zb[row_l * ZPITCH + col32 * 4 + w] = fmaf(accB[r], INV_S, accA[r]) + bsv;
    }
    asm volatile("s_waitcnt lgkmcnt(0)" ::: "memory");
    __builtin_amdgcn_s_barrier();

    // epilogue stage 2: z += px, cell update (c in regs), h via agent stores
    {
      float* hcur = ((s & 1) ? hB : hA) + (size_t)(m0 + arow) * H_DIM + nc0 + q8 * 4;
      float hnv[4];
      #pragma unroll
      for (int cc = 0; cc < 4; ++cc) {
        float4 zq = *(const float4*)&zb[arow * ZPITCH + (q8 * 4 + cc) * 4];
        float zi = zq.x + pxa[0][cc];
        float zf = zq.y + pxa[1][cc];
        float zg = zq.z + pxa[2][cc];
        float zo = zq.w + pxa[3][cc];
        float cn = sigf(zf) * c_reg[cc] + sigf(zi) * tanhf(zg);
        c_reg[cc] = cn;
        hnv[cc] = sigf(zo) * tanhf(cn);
      }
      astore4(hcur, make_float4(hnv[0], hnv[1], hnv[2], hnv[3]));
    }
    group_arrive(flag); ++E;

    // ================= declog epoch (decoder only) =================
    if (!enc) {
      const int t = s - S_LEN;
      group_wait(flag, 8 * E);

      const int r0d = m0 + nb * 4;
      const float* hnow = (s & 1) ? hB : hA;
      float (*dAs)[260] = (float (*)[260])smem;                  // 4160 f
      float (*bv)[256]  = (float (*)[256])((char*)smem + 17408); // 4 KB
      int   (*bi)[256]  = (int (*)[256])((char*)smem + 21504);   // 4 KB

      {
        int srow = tid >> 6;
        int scol = (tid & 63) * 4;
        float4 hv4 = aload4(hnow + (size_t)(r0d + srow) * H_DIM + scol);
        *(float4*)&dAs[srow][scol] = hv4;
      }
      __syncthreads();

      const int c0 = tid * 2;
      const float* w0p = fcW + (size_t)c0 * H_DIM;
      const float* w1p = w0p + H_DIM;
      float acc[4][2] = {};

      #pragma unroll 1
      for (int k0 = 0; k0 < H_DIM; k0 += 16) {
        float4 b0[4], b1[4];
        #pragma unroll
        for (int q = 0; q < 4; ++q) {
          b0[q] = *(const float4*)(w0p + k0 + q * 4);
          b1[q] = *(const float4*)(w1p + k0 + q * 4);
        }
        #pragma unroll
        for (int q = 0; q < 4; ++q) {
          #pragma unroll
          for (int r = 0; r < 4; ++r) {
            float4 a = *(const float4*)&dAs[r][k0 + q * 4];
            acc[r][0] = fmaf(a.x, b0[q].x, acc[r][0]);
            acc[r][0] = fmaf(a.y, b0[q].y, acc[r][0]);
            acc[r][0] = fmaf(a.z, b0[q].z, acc[r][0]);
            acc[r][0] = fmaf(a.w, b0[q].w, acc[r][0]);
            acc[r][1] = fmaf(a.x, b1[q].x, acc[r][1]);
            acc[r][1] = fmaf(a.y, b1[q].y, acc[r][1]);
            acc[r][1] = fmaf(a.z, b1[q].z, acc[r][1]);
            acc[r][1] = fmaf(a.w, b1[q].w, acc[r][1]);
          }
        }
      }

      const float fb0 = fcb[c0];
      const float fb1 = fcb[c0 + 1];
      #pragma unroll
      for (int r = 0; r < 4; ++r) {
        float z0 = acc[r][0] + fb0;
        float z1 = acc[r][1] + fb1;
        *(float2*)(out + ((size_t)(r0d + r) * T + t) * V_DIM + c0) = make_float2(z0, z1);
        float v = z0; int ix = c0;
        if (z1 > v) { v = z1; ix = c0 + 1; }
        bv[r][tid] = v;
        bi[r][tid] = ix;
      }
      __syncthreads();

      {
        const int wv = w;              // wave wv reduces row wv (4 rows, 4 waves)
        float best = bv[wv][lane];
        int   bidx = bi[wv][lane];
        #pragma unroll
        for (int ss = 1; ss < 4; ++ss) {
          float ov = bv[wv][lane + 64 * ss];
          int   oi = bi[wv][lane + 64 * ss];
          if (ov > best || (ov == best && oi < bidx)) { best = ov; bidx = oi; }
        }
        #pragma unroll
        for (int off = 32; off; off >>= 1) {
          float ov = __shfl_xor(best, off);
          int   oi = __shfl_xor(bidx, off);
          if (ov > best || (ov == best && oi < bidx)) { best = ov; bidx = oi; }
        }
        if (lane == 0)
          __hip_atomic_store(&tok[r0d + wv], bidx, __ATOMIC_RELAXED, __HIP_MEMORY_SCOPE_AGENT);
      }
      group_arrive(flag); ++E;
    }
  }
}

// ---------------------------------------------------------------------------
// FALLBACK path — EXACT r19 kernels (used only if 2 blocks/CU not achievable).
// ---------------------------------------------------------------------------
__launch_bounds__(256, 2)
__global__ void lstm_mfma_kernel(const float* __restrict__ pcomp,
                                 const int* __restrict__ idx_src, int idx_stride, int idx_off,
                                 const unsigned short* __restrict__ Wf,
                                 const float* __restrict__ bih, const float* __restrict__ bhh,
                                 const float* __restrict__ h_in,
                                 float* __restrict__ h_out, float* __restrict__ c)
{
  __shared__ __align__(16) unsigned short smem[2 * A_SHORTS];
  unsigned short* Ax1 = smem;
  unsigned short* Ax2 = smem + A_SHORTS;

  const int tid  = threadIdx.x;
  const int lane = tid & 63;
  const int w    = tid >> 6;
  const int m0 = blockIdx.x * 32;
  const int nb = blockIdx.y;
  const int nc0 = nb * 32;

  const int arow = tid >> 3;
  const int q8   = tid & 7;
  const int token = idx_src[(size_t)(m0 + arow) * idx_stride + idx_off];
  const float* hsrc = h_in + (size_t)(m0 + arow) * H_DIM;
  const int col32 = lane & 31;
  const int lhi   = lane >> 5;

  const unsigned short* wb = Wf + (size_t)nb * (W_TILES * TILE_SHORTS)
                           + (size_t)(w * 4) * 512 + (size_t)lane * 8;

  f32x16 accA, accB;
  #pragma unroll
  for (int r = 0; r < 16; ++r) { accA[r] = 0.f; accB[r] = 0.f; }

  uint4 pA[4], pB[4], pC[4], pD[4];

  LOADT(0, pA); LOADT(1, pB); LOADT(2, pC);
  stage_A12(Ax1, Ax2, hsrc, arow, q8);
  asm volatile("s_waitcnt lgkmcnt(0)" ::: "memory");
  __builtin_amdgcn_s_barrier();

  LOADT(3, pD);  MFMAT(0, pA, accA, Ax1);
  LOADT(4, pA);  MFMAT(1, pB, accA, Ax1);
  LOADT(5, pB);  MFMAT(2, pC, accA, Ax1);
  LOADT(6, pC);  MFMAT(3, pD, accA, Ax1);
  LOADT(7, pD);  MFMAT(4, pA, accB, Ax1);
  LOADT(8, pA);  MFMAT(5, pB, accB, Ax1);
  LOADT(9, pB);  MFMAT(6, pC, accB, Ax1);
  LOADT(10, pC); MFMAT(7, pD, accB, Ax1);
  LOADT(11, pD); MFMAT(8, pA, accB, Ax2);

  const float* cp0 = c + (size_t)(m0 + arow) * H_DIM + nc0 + q8 * 4;
  float4 cold = *(const float4*)(cp0);
  const float* pxr = pcomp + (size_t)token * 1024 + nc0 + q8 * 4;
  float pxa[4][4];
  #pragma unroll
  for (int gg = 0; gg < 4; ++gg) {
    float4 t = *(const float4*)(pxr + gg * H_DIM);
    pxa[gg][0] = t.x; pxa[gg][1] = t.y; pxa[gg][2] = t.z; pxa[gg][3] = t.w;
  }

  MFMAT(9, pB, accB, Ax2);
  MFMAT(10, pC, accB, Ax2);
  MFMAT(11, pD, accB, Ax2);

  const float bsv = bih[w * H_DIM + nc0 + col32] + bhh[w * H_DIM + nc0 + col32];
  float* zb = (float*)smem;
  asm volatile("s_waitcnt lgkmcnt(0)" ::: "memory");
  __builtin_amdgcn_s_barrier();
  #pragma unroll
  for (int r = 0; r < 16; ++r) {
    int row_l = (r & 3) + 8 * (r >> 2) + 4 * lhi;
    zb[row_l * ZPITCH + col32 * 4 + w] = fmaf(accB[r], INV_S, accA[r]) + bsv;
  }
  asm volatile("s_waitcnt lgkmcnt(0)" ::: "memory");
  __builtin_amdgcn_s_barrier();
  {
    float* hp  = h_out + (size_t)(m0 + arow) * H_DIM + nc0 + q8 * 4;
    float* cpw = (float*)cp0;
    float cov[4] = {cold.x, cold.y, cold.z, cold.w};
    float cnv[4], hnv[4];
    #pragma unroll
    for (int cc = 0; cc < 4; ++cc) {
      float4 zq = *(const float4*)&zb[arow * ZPITCH + (q8 * 4 + cc) * 4];
      float zi = zq.x + pxa[0][cc];
      float zf = zq.y + pxa[1][cc];
      float zg = zq.z + pxa[2][cc];
      float zo = zq.w + pxa[3][cc];
      float cn = sigf(zf) * cov[cc] + sigf(zi) * tanhf(zg);
      cnv[cc] = cn;
      hnv[cc] = sigf(zo) * tanhf(cn);
    }
    *(float4*)cpw = make_float4(cnv[0], cnv[1], cnv[2], cnv[3]);
    *(float4*)hp  = make_float4(hnv[0], hnv[1], hnv[2], hnv[3]);
  }
}

__launch_bounds__(256)
__global__ void declog_kernel(const float* __restrict__ h, const float* __restrict__ fcW,
                              const float* __restrict__ fcb, float* __restrict__ out,
                              int* __restrict__ tok, int t, int T)
{
  __shared__ float bv[8][256];
  __shared__ int   bi[8][256];
  const int tid  = threadIdx.x;
  const int lane = tid & 63;
  const int wv   = tid >> 6;
  const int r0   = blockIdx.x * 8;
  const int c0   = tid * 2;
  const float* hb  = h + (size_t)r0 * H_DIM;
  const float* w0p = fcW + (size_t)c0 * H_DIM;
  const float* w1p = w0p + H_DIM;
  float acc[8][2] = {};
  #pragma unroll 1
  for (int k0 = 0; k0 < H_DIM; k0 += 16) {
    float4 b0[4], b1[4];
    #pragma unroll
    for (int q = 0; q < 4; ++q) {
      b0[q] = *(const float4*)(w0p + k0 + q * 4);
      b1[q] = *(const float4*)(w1p + k0 + q * 4);
    }
    #pragma unroll
    for (int q = 0; q < 4; ++q) {
      #pragma unroll
      for (int r = 0; r < 8; ++r) {
        float4 a = *(const float4*)(hb + (size_t)r * H_DIM + k0 + q * 4);
        acc[r][0] = fmaf(a.x, b0[q].x, acc[r][0]);
        acc[r][0] = fmaf(a.y, b0[q].y, acc[r][0]);
        acc[r][0] = fmaf(a.z, b0[q].z, acc[r][0]);
        acc[r][0] = fmaf(a.w, b0[q].w, acc[r][0]);
        acc[r][1] = fmaf(a.x, b1[q].x, acc[r][1]);
        acc[r][1] = fmaf(a.y, b1[q].y, acc[r][1]);
        acc[r][1] = fmaf(a.z, b1[q].z, acc[r][1]);
        acc[r][1] = fmaf(a.w, b1[q].w, acc[r][1]);
      }
    }
  }
  const float fb0 = fcb[c0];
  const float fb1 = fcb[c0 + 1];
  #pragma unroll
  for (int r = 0; r < 8; ++r) {
    float z0 = acc[r][0] + fb0;
    float z1 = acc[r][1] + fb1;
    *(float2*)(out + (size_t)(r0 + r) * T * V_DIM + (size_t)t * V_DIM + c0) = make_float2(z0, z1);
    float v = z0; int ix = c0;
    if (z1 > v) { v = z1; ix = c0 + 1; }
    bv[r][tid] = v;
    bi[r][tid] = ix;
  }
  __syncthreads();
  #pragma unroll
  for (int rr = 0; rr < 2; ++rr) {
    int r = wv * 2 + rr;
    float best = bv[r][lane];
    int   bidx = bi[r][lane];
    #pragma unroll
    for (int ss = 1; ss < 4; ++ss) {
      float ov = bv[r][lane + 64 * ss];
      int   oi = bi[r][lane + 64 * ss];
      if (ov > best || (ov == best && oi < bidx)) { best = ov; bidx = oi; }
    }
    #pragma unroll
    for (int off = 32; off; off >>= 1) {
      float ov = __shfl_xor(best, off);
      int   oi = __shfl_xor(bidx, off);
      if (ov > best || (ov == best && oi < bidx)) { best = ov; bidx = oi; }
    }
    if (lane == 0) tok[r0 + r] = bidx;
  }
}

extern "C" void kernel_launch(void* const* d_in, const int* in_sizes, int n_in,
                              void* d_out, int out_size, void* d_ws, size_t ws_size,
                              hipStream_t stream) {
  const int*   source  = (const int*)d_in[0];
  const float* enc_emb = (const float*)d_in[2];
  const float* enc_Wih = (const float*)d_in[3];
  const float* enc_Whh = (const float*)d_in[4];
  const float* enc_bih = (const float*)d_in[5];
  const float* enc_bhh = (const float*)d_in[6];
  const float* dec_emb = (const float*)d_in[7];
  const float* dec_Wih = (const float*)d_in[8];
  const float* dec_Whh = (const float*)d_in[9];
  const float* dec_bih = (const float*)d_in[10];
  const float* dec_bhh = (const float*)d_in[11];
  const float* fc_W    = (const float*)d_in[12];
  const float* fc_b    = (const float*)d_in[13];
  float* out = (float*)d_out;

  const int B = in_sizes[0] / S_LEN;              // 2048
  int T = out_size / (B * V_DIM);                 // 48

  const size_t BH = (size_t)B * H_DIM;
  const size_t WFSZ = (size_t)8 * W_TILES * TILE_SHORTS;
  float* hA  = (float*)d_ws;
  float* hB  = hA + BH;
  float* c   = hB + BH;
  int*   tok = (int*)(c + BH);
  int*   flags = tok + B;                          // 64 ints
  unsigned short* We = (unsigned short*)(flags + 64);
  unsigned short* Wd = We + WFSZ;
  float* PE = (float*)(Wd + WFSZ);
  float* PD = PE + (size_t)V_DIM * 1024;

  prep_weights<<<dim3(128 + 1024 + 64), dim3(256), 0, stream>>>(
      enc_emb, dec_emb, enc_Wih, enc_Whh, dec_Wih, dec_Whh,
      We, Wd, PE, PD, hB, c, tok, flags);

  int nblk = 0;
  hipOccupancyMaxActiveBlocksPerMultiprocessor(&nblk,
      reinterpret_cast<const void*>(&seq2seq_mega), 256, 0);

  if (nblk >= 2) {
    void* args[] = {
      (void*)&source, (void*)&PE, (void*)&PD, (void*)&We, (void*)&Wd,
      (void*)&enc_bih, (void*)&enc_bhh, (void*)&dec_bih, (void*)&dec_bhh,
      (void*)&fc_W, (void*)&fc_b,
      (void*)&out, (void*)&hA, (void*)&hB, (void*)&tok, (void*)&flags, (void*)&T
    };
    hipLaunchCooperativeKernel(reinterpret_cast<const void*>(&seq2seq_mega),
                               dim3(512), dim3(256), args, 0, stream);
  } else {
    dim3 blk(256);
    dim3 g_lstm(B / 32, H_DIM / 32);
    dim3 g_declog(B / 8);
    const float* hin = hB;
    float* hout = hA;
    for (int s = 0; s < S_LEN; ++s) {
      lstm_mfma_kernel<<<g_lstm, blk, 0, stream>>>(
          PE, source, S_LEN, s, We, enc_bih, enc_bhh, hin, hout, c);
      const float* tmp = hout; hout = (float*)hin; hin = tmp;
    }
    for (int t = 0; t < T; ++t) {
      lstm_mfma_kernel<<<g_lstm, blk, 0, stream>>>(
          PD, tok, 1, 0, Wd, dec_bih, dec_bhh, hin, hout, c);
      const float* tmp = hout; hout = (float*)hin; hin = tmp;
      declog_kernel<<<g_declog, blk, 0, stream>>>(hin, fc_W, fc_b, out, tok, t, T);
    }
  }
}

// Round 21
// 1678.057 us; speedup vs baseline: 1.0011x; 1.0011x over previous
//
#include <hip/hip_runtime.h>
#include <cmath>

#define S_LEN 32
#define E_DIM 128
#define H_DIM 256
#define V_DIM 512
#define NTILE 12            // h-only K=256: 0-3 a1w1, 4-7 a1w2s, 8-11 a2s*w1
#define W_TILES 8           // unique W tiles stored (tiles 8-11 reuse 0-3)
#define TILE_SHORTS 8192    // 16 frags x 64 lanes x 8 halfs = 16 KB
#define A_SHORTS 8192       // per level: 16 k-chunks x 64 lanes x 8 halfs = 16 KB
#define ZPITCH 132          // z-buffer row pitch (words)

typedef _Float16 f16x8v __attribute__((ext_vector_type(8)));
typedef float f32x16 __attribute__((ext_vector_type(16)));

#define SCALE_S 4096.0f          // 2^12
#define INV_S   2.44140625e-4f   // 2^-12 (exact)

__device__ __forceinline__ float sigf(float x) { return 1.0f / (1.0f + expf(-x)); }

template<int L>
__device__ __forceinline__ unsigned short lvl_f16(float x) {
  _Float16 h1 = (_Float16)x;                       // RNE
  if (L == 1) return __builtin_bit_cast(unsigned short, h1);
  _Float16 h2 = (_Float16)((x - (float)h1) * SCALE_S);
  return __builtin_bit_cast(unsigned short, h2);
}

// ---------------------------------------------------------------------------
// prep, 3 roles by blockIdx:
//  [0,128):    Whh fragment stream (h-only K=256), fp16 2-level, 32x32x16
//              layout: fi=g*4+kc, lane row n=g*256+nb*32+(l&31),
//              k = jj*64 + kc*16 + (l>>5)*8 + e. Tiles 0-3 w1, 4-7 w2s.
//  [128,1152): precomp P[set][v][n] = emb[v] @ Wih[n]^T, exact f32, k ascending.
//  [1152,1216): zero-init h0 / c / tok.
// ---------------------------------------------------------------------------
__global__ void prep_weights(const float* __restrict__ eemb, const float* __restrict__ demb,
                             const float* __restrict__ eWih, const float* __restrict__ eWhh,
                             const float* __restrict__ dWih, const float* __restrict__ dWhh,
                             unsigned short* __restrict__ We, unsigned short* __restrict__ Wd,
                             float* __restrict__ PE, float* __restrict__ PD,
                             float* __restrict__ h0, float* __restrict__ c,
                             int* __restrict__ tok)
{
  const int b = blockIdx.x;
  if (b >= 1152) {                        // ---- init tail: 64 blocks
    const int pb = b - 1152;
    const int gt = pb * 256 + threadIdx.x;     // 0..16383
    float4 z = make_float4(0.f, 0.f, 0.f, 0.f);
    float4* p0 = (float4*)h0;
    float4* pc = (float4*)c;
    for (int i = gt; i < 131072; i += 16384) { p0[i] = z; pc[i] = z; }
    if (gt < 2048) tok[gt] = 0;
    return;
  }
  if (b >= 128) {                         // ---- precomp: 1024 blocks
    const int pb  = b - 128;
    const int set = pb >> 9;              // 0 enc, 1 dec
    const int v   = pb & 511;
    const float* Wih  = set ? dWih : eWih;
    const float* embr = (set ? demb : eemb) + (size_t)v * E_DIM;
    float* dst = (set ? PD : PE) + (size_t)v * 1024;
    const int n0 = threadIdx.x * 4;
    float acc[4] = {0.f, 0.f, 0.f, 0.f};
    #pragma unroll 4
    for (int k0 = 0; k0 < E_DIM; k0 += 4) {
      float4 e = *(const float4*)(embr + k0);
      #pragma unroll
      for (int i = 0; i < 4; ++i) {
        float4 wv = *(const float4*)(Wih + (size_t)(n0 + i) * E_DIM + k0);
        acc[i] = fmaf(e.x, wv.x, acc[i]);
        acc[i] = fmaf(e.y, wv.y, acc[i]);
        acc[i] = fmaf(e.z, wv.z, acc[i]);
        acc[i] = fmaf(e.w, wv.w, acc[i]);
      }
    }
    *(float4*)(dst + n0) = make_float4(acc[0], acc[1], acc[2], acc[3]);
    return;
  }
  // ---- Whh fragment stream: 128 blocks
  const int j    = b % W_TILES;           // 0..7
  const int rest = b / W_TILES;
  const int nb   = rest & 7;
  const int set  = rest >> 3;
  const float* Whh = set ? dWhh : eWhh;
  unsigned short* dst = (set ? Wd : We) + ((size_t)nb * W_TILES + j) * TILE_SHORTS;
  const int lvl = (j < 4) ? 1 : 2;
  const int jj  = j & 3;

  for (int cpos = threadIdx.x; cpos < 1024; cpos += 256) {
    int fi = cpos >> 6, l = cpos & 63;
    int g = fi >> 2, kc = fi & 3;
    int n  = g * H_DIM + nb * 32 + (l & 31);
    int kk = jj * 64 + kc * 16 + (l >> 5) * 8;
    unsigned short o8[8];
    #pragma unroll
    for (int e = 0; e < 8; ++e) {
      float v = Whh[(size_t)n * H_DIM + kk + e];
      o8[e] = (lvl == 1) ? lvl_f16<1>(v) : lvl_f16<2>(v);
    }
    uint4 pk;
    pk.x = (unsigned)o8[0] | ((unsigned)o8[1] << 16);
    pk.y = (unsigned)o8[2] | ((unsigned)o8[3] << 16);
    pk.z = (unsigned)o8[4] | ((unsigned)o8[5] << 16);
    pk.w = (unsigned)o8[6] | ((unsigned)o8[7] << 16);
    *(uint4*)&dst[(size_t)cpos * 8] = pk;
  }
}

// stage BOTH fp16 levels of A = h_in (K=256) into 32x32x16 A-fragment layout:
// value (row, kA): chunk = kA>>4, lane = row + ((kA>>3)&1)*32, e = kA&7.
__device__ __forceinline__ void stage_A12(unsigned short* Ax1, unsigned short* Ax2,
                                          const float* __restrict__ hsrc,
                                          int arow, int q8) {
  #pragma unroll
  for (int j = 0; j < 8; ++j) {
    int kA = q8 * 4 + 32 * j;                 // covers 0..255 (multiples of 4)
    float4 v = *(const float4*)(hsrc + kA);
    _Float16 a1x = (_Float16)v.x, a1y = (_Float16)v.y,
             a1z = (_Float16)v.z, a1w = (_Float16)v.w;
    _Float16 a2x = (_Float16)((v.x - (float)a1x) * SCALE_S);
    _Float16 a2y = (_Float16)((v.y - (float)a1y) * SCALE_S);
    _Float16 a2z = (_Float16)((v.z - (float)a1z) * SCALE_S);
    _Float16 a2w = (_Float16)((v.w - (float)a1w) * SCALE_S);
    int lane_w = arow + ((kA >> 3) & 1) * 32;
    int idx = ((kA >> 4) * 64 + lane_w) * 8 + (kA & 7);
    uint2 p1, p2;
    p1.x = (unsigned)__builtin_bit_cast(unsigned short, a1x)
         | ((unsigned)__builtin_bit_cast(unsigned short, a1y) << 16);
    p1.y = (unsigned)__builtin_bit_cast(unsigned short, a1z)
         | ((unsigned)__builtin_bit_cast(unsigned short, a1w) << 16);
    p2.x = (unsigned)__builtin_bit_cast(unsigned short, a2x)
         | ((unsigned)__builtin_bit_cast(unsigned short, a2y) << 16);
    p2.y = (unsigned)__builtin_bit_cast(unsigned short, a2z)
         | ((unsigned)__builtin_bit_cast(unsigned short, a2w) << 16);
    *(uint2*)&Ax1[idx] = p1;
    *(uint2*)&Ax2[idx] = p2;
  }
}

// ---------------------------------------------------------------------------
// LSTM step: h-part GEMM (K=256, fp16 2-level 3-term, 32x32x16 gate-per-wave)
// + precomputed x-part added in the epilogue (exact f32 from P[token]).
// Block: 32 rows x 32 hidden cols; wave w = gate w. 12 tiles, reg-streamed B
// (4 buffers, 3-tile lookahead), no per-tile barriers. LDS 32 KB.
// ---------------------------------------------------------------------------
__launch_bounds__(256, 2)
__global__ void lstm_mfma_kernel(const float* __restrict__ pcomp,   // [512][1024]
                                 const int* __restrict__ idx_src, int idx_stride, int idx_off,
                                 const unsigned short* __restrict__ Wf,
                                 const float* __restrict__ bih, const float* __restrict__ bhh,
                                 const float* __restrict__ h_in,
                                 float* __restrict__ h_out, float* __restrict__ c)
{
  __shared__ __align__(16) unsigned short smem[2 * A_SHORTS];  // 32 KB
  unsigned short* Ax1 = smem;                 // a1 fragments (z-buffer alias)
  unsigned short* Ax2 = smem + A_SHORTS;      // a2s fragments

  const int tid  = threadIdx.x;
  const int lane = tid & 63;
  const int w    = tid >> 6;            // wave = gate 0..3
  const int m0 = blockIdx.x * 32;
  const int nb = blockIdx.y;
  const int nc0 = nb * 32;

  const int arow = tid >> 3;            // 0..31 (also epilogue row er)
  const int q8   = tid & 7;             // (also epilogue col group ec)
  const int token = idx_src[(size_t)(m0 + arow) * idx_stride + idx_off];
  const float* hsrc = h_in + (size_t)(m0 + arow) * H_DIM;

  const int col32 = lane & 31;
  const int lhi   = lane >> 5;

  // per-wave B fragment base: frags (w*4 + kc), lane*8
  const unsigned short* wbase = Wf + (size_t)nb * (W_TILES * TILE_SHORTS)
                                   + (size_t)(w * 4) * 512 + (size_t)lane * 8;

  f32x16 accA, accB;
  #pragma unroll
  for (int r = 0; r < 16; ++r) { accA[r] = 0.f; accB[r] = 0.f; }

  uint4 pA[4], pB[4], pC[4], pD[4];

#define LOADT(J, P)                                                            \
  {                                                                            \
    const unsigned short* bsrc = wbase + (size_t)((J) & 7) * TILE_SHORTS;      \
    _Pragma("unroll")                                                          \
    for (int kc = 0; kc < 4; ++kc) P[kc] = *(const uint4*)(bsrc + (size_t)kc * 512); \
  }

#define MFMAT(J, P, ACCX, AXB)                                                 \
  {                                                                            \
    _Pragma("unroll")                                                          \
    for (int kc = 0; kc < 4; ++kc) {                                           \
      f16x8v af = *(const f16x8v*)&AXB[(((J) & 3) * 4 + kc) * 512 + lane * 8]; \
      f16x8v bfr = __builtin_bit_cast(f16x8v, P[kc]);                          \
      ACCX = __builtin_amdgcn_mfma_f32_32x32x16_f16(af, bfr, ACCX, 0, 0, 0);   \
    }                                                                          \
  }

  // issue first B tiles BEFORE A staging (their L2 latency hides under cvt)
  LOADT(0, pA); LOADT(1, pB); LOADT(2, pC);

  stage_A12(Ax1, Ax2, hsrc, arow, q8);
  asm volatile("s_waitcnt lgkmcnt(0)" ::: "memory");   // A writes visible
  __builtin_amdgcn_s_barrier();                        // B loads stay in flight

  LOADT(3, pD);  MFMAT(0, pA, accA, Ax1);
  LOADT(4, pA);  MFMAT(1, pB, accA, Ax1);
  LOADT(5, pB);  MFMAT(2, pC, accA, Ax1);
  LOADT(6, pC);  MFMAT(3, pD, accA, Ax1);
  LOADT(7, pD);  MFMAT(4, pA, accB, Ax1);
  LOADT(8, pA);  MFMAT(5, pB, accB, Ax1);
  LOADT(9, pB);  MFMAT(6, pC, accB, Ax1);
  LOADT(10, pC); MFMAT(7, pD, accB, Ax1);
  LOADT(11, pD); MFMAT(8, pA, accB, Ax2);

  // ---- prefetch c and precomp-x rows (covered by the last 3 MFMA tiles)
  const int er = arow;                   // local row 0..31
  const int ec = q8;                     // float4-col 0..7
  const float* cp0 = c + (size_t)(m0 + er) * H_DIM + nc0 + ec * 4;
  float4 cold = *(const float4*)(cp0);
  const float* pxr = pcomp + (size_t)token * 1024 + nc0 + ec * 4;
  float pxa[4][4];
  #pragma unroll
  for (int g = 0; g < 4; ++g) {
    float4 t = *(const float4*)(pxr + g * H_DIM);
    pxa[g][0] = t.x; pxa[g][1] = t.y; pxa[g][2] = t.z; pxa[g][3] = t.w;
  }

  MFMAT(9, pB, accB, Ax2);
  MFMAT(10, pC, accB, Ax2);
  MFMAT(11, pD, accB, Ax2);

#undef LOADT
#undef MFMAT

  // ---- epilogue stage 1: combine scales + bias -> z LDS buffer (alias A)
  const float bsv = bih[w * H_DIM + nc0 + col32] + bhh[w * H_DIM + nc0 + col32];

  float* zb = (float*)smem;
  asm volatile("s_waitcnt lgkmcnt(0)" ::: "memory");
  __builtin_amdgcn_s_barrier();          // all waves done reading Ax1/Ax2

  #pragma unroll
  for (int r = 0; r < 16; ++r) {
    int row_l = (r & 3) + 8 * (r >> 2) + 4 * lhi;
    zb[row_l * ZPITCH + col32 * 4 + w] = fmaf(accB[r], INV_S, accA[r]) + bsv;
  }

  asm volatile("s_waitcnt lgkmcnt(0)" ::: "memory");
  __builtin_amdgcn_s_barrier();          // z visible

  // ---- epilogue stage 2: z += precomp-x, cell update, coalesced f4 c/h I/O
  {
    float* hp  = h_out + (size_t)(m0 + er) * H_DIM + nc0 + ec * 4;
    float* cpw = (float*)cp0;
    float cov[4] = {cold.x, cold.y, cold.z, cold.w};
    float cnv[4], hnv[4];
    #pragma unroll
    for (int cc = 0; cc < 4; ++cc) {
      float4 zq = *(const float4*)&zb[er * ZPITCH + (ec * 4 + cc) * 4];
      float zi = zq.x + pxa[0][cc];
      float zf = zq.y + pxa[1][cc];
      float zg = zq.z + pxa[2][cc];
      float zo = zq.w + pxa[3][cc];
      float cn = sigf(zf) * cov[cc] + sigf(zi) * tanhf(zg);
      cnv[cc] = cn;
      hnv[cc] = sigf(zo) * tanhf(cn);
    }
    *(float4*)cpw = make_float4(cnv[0], cnv[1], cnv[2], cnv[3]);
    *(float4*)hp  = make_float4(hnv[0], hnv[1], hnv[2], hnv[3]);
  }
}

// ---------------------------------------------------------------------------
// declog v4 — EXACT rounds 13-19 version (known-good, ~6 us).
// ---------------------------------------------------------------------------
__launch_bounds__(256)
__global__ void declog_kernel(const float* __restrict__ h,    // [B, H]
                              const float* __restrict__ fcW,  // [V, H]
                              const float* __restrict__ fcb,  // [V]
                              float* __restrict__ out,        // [B, T, V]
                              int* __restrict__ tok,          // [B]
                              int t, int T)
{
  __shared__ float bv[8][256];
  __shared__ int   bi[8][256];

  const int tid  = threadIdx.x;
  const int lane = tid & 63;
  const int wv   = tid >> 6;
  const int r0   = blockIdx.x * 8;
  const int c0   = tid * 2;             // this thread's 2 vocab cols

  const float* hb  = h + (size_t)r0 * H_DIM;
  const float* w0p = fcW + (size_t)c0 * H_DIM;
  const float* w1p = w0p + H_DIM;

  float acc[8][2] = {};                 // [row][col]

  #pragma unroll 1
  for (int k0 = 0; k0 < H_DIM; k0 += 16) {
    float4 b0[4], b1[4];
    #pragma unroll
    for (int q = 0; q < 4; ++q) {
      b0[q] = *(const float4*)(w0p + k0 + q * 4);
      b1[q] = *(const float4*)(w1p + k0 + q * 4);
    }
    #pragma unroll
    for (int q = 0; q < 4; ++q) {
      #pragma unroll
      for (int r = 0; r < 8; ++r) {
        float4 a = *(const float4*)(hb + (size_t)r * H_DIM + k0 + q * 4); // uniform
        acc[r][0] = fmaf(a.x, b0[q].x, acc[r][0]);
        acc[r][0] = fmaf(a.y, b0[q].y, acc[r][0]);
        acc[r][0] = fmaf(a.z, b0[q].z, acc[r][0]);
        acc[r][0] = fmaf(a.w, b0[q].w, acc[r][0]);
        acc[r][1] = fmaf(a.x, b1[q].x, acc[r][1]);
        acc[r][1] = fmaf(a.y, b1[q].y, acc[r][1]);
        acc[r][1] = fmaf(a.z, b1[q].z, acc[r][1]);
        acc[r][1] = fmaf(a.w, b1[q].w, acc[r][1]);
      }
    }
  }

  const float fb0 = fcb[c0];
  const float fb1 = fcb[c0 + 1];
  #pragma unroll
  for (int r = 0; r < 8; ++r) {
    float z0 = acc[r][0] + fb0;
    float z1 = acc[r][1] + fb1;
    *(float2*)(out + (size_t)(r0 + r) * T * V_DIM + (size_t)t * V_DIM + c0)
        = make_float2(z0, z1);
    float v = z0; int ix = c0;
    if (z1 > v) { v = z1; ix = c0 + 1; }   // strict >: first index kept
    bv[r][tid] = v;
    bi[r][tid] = ix;
  }
  __syncthreads();

  #pragma unroll
  for (int rr = 0; rr < 2; ++rr) {
    int r = wv * 2 + rr;
    float best = bv[r][lane];
    int   bidx = bi[r][lane];
    #pragma unroll
    for (int s = 1; s < 4; ++s) {
      float ov = bv[r][lane + 64 * s];
      int   oi = bi[r][lane + 64 * s];
      if (ov > best || (ov == best && oi < bidx)) { best = ov; bidx = oi; }
    }
    #pragma unroll
    for (int off = 32; off; off >>= 1) {
      float ov = __shfl_xor(best, off);
      int   oi = __shfl_xor(bidx, off);
      if (ov > best || (ov == best && oi < bidx)) { best = ov; bidx = oi; }
    }
    if (lane == 0) tok[r0 + r] = bidx;
  }
}

extern "C" void kernel_launch(void* const* d_in, const int* in_sizes, int n_in,
                              void* d_out, int out_size, void* d_ws, size_t ws_size,
                              hipStream_t stream) {
  const int*   source  = (const int*)d_in[0];
  const float* enc_emb = (const float*)d_in[2];
  const float* enc_Wih = (const float*)d_in[3];
  const float* enc_Whh = (const float*)d_in[4];
  const float* enc_bih = (const float*)d_in[5];
  const float* enc_bhh = (const float*)d_in[6];
  const float* dec_emb = (const float*)d_in[7];
  const float* dec_Wih = (const float*)d_in[8];
  const float* dec_Whh = (const float*)d_in[9];
  const float* dec_bih = (const float*)d_in[10];
  const float* dec_bhh = (const float*)d_in[11];
  const float* fc_W    = (const float*)d_in[12];
  const float* fc_b    = (const float*)d_in[13];
  float* out = (float*)d_out;

  const int B = in_sizes[0] / S_LEN;              // 2048
  const int T = out_size / (B * V_DIM);           // 48

  const size_t BH = (size_t)B * H_DIM;
  const size_t WFSZ = (size_t)8 * W_TILES * TILE_SHORTS;   // shorts per set (1 MB)
  float* h0  = (float*)d_ws;
  float* h1  = h0 + BH;
  float* c   = h1 + BH;
  int*   tok = (int*)(c + BH);
  unsigned short* We = (unsigned short*)(tok + B);
  unsigned short* Wd = We + WFSZ;
  float* PE = (float*)(Wd + WFSZ);                // [512][1024] f32
  float* PD = PE + (size_t)V_DIM * 1024;

  prep_weights<<<dim3(128 + 1024 + 64), dim3(256), 0, stream>>>(
      enc_emb, dec_emb, enc_Wih, enc_Whh, dec_Wih, dec_Whh,
      We, Wd, PE, PD, h0, c, tok);

  dim3 blk(256);
  dim3 g_lstm(B / 32, H_DIM / 32);    // (64, 8) = 512 blocks, 2 blocks/CU
  dim3 g_declog(B / 8);               // 256 blocks

  const float* hin = h0;
  float* hout = h1;

  // ---- encoder ----
  for (int s = 0; s < S_LEN; ++s) {
    lstm_mfma_kernel<<<g_lstm, blk, 0, stream>>>(
        PE, source, S_LEN, s, We, enc_bih, enc_bhh, hin, hout, c);
    const float* tmp = hout; hout = (float*)hin; hin = tmp;
  }

  // ---- decoder (greedy, autoregressive) ----
  for (int t = 0; t < T; ++t) {
    lstm_mfma_kernel<<<g_lstm, blk, 0, stream>>>(
        PD, tok, 1, 0, Wd, dec_bih, dec_bhh, hin, hout, c);
    const float* tmp = hout; hout = (float*)hin; hin = tmp;
    declog_kernel<<<g_declog, blk, 0, stream>>>(hin, fc_W, fc_b, out, tok, t, T);
  }
}